// Round 2
// baseline (2503.856 us; speedup 1.0000x reference)
//
#include <hip/hip_runtime.h>

#define N_NODES 50000
#define N_EDGES 800000
#define BATCH 8
#define CH 64
#define WSZ (CH * CH)
#define NPB 8            // nodes per block (one wave each)
#define NTHREADS 512

// ---------------- CSR build ----------------

__global__ void hist_kernel(const int* __restrict__ dst, int* __restrict__ cursor, int E) {
    int e = blockIdx.x * blockDim.x + threadIdx.x;
    if (e < E) atomicAdd(&cursor[dst[e]], 1);
}

// counts in `cursor` on entry; exit: row_ptr = exclusive scan (n+1), cursor = copy.
__global__ void scan_kernel(int* cursor, int* __restrict__ row_ptr, int n) {
    const int T = 1024;
    int tid = threadIdx.x;
    int per = (n + T - 1) / T;
    int s = tid * per;
    int e = s + per; if (e > n) e = n;
    int sum = 0;
    for (int i = s; i < e; ++i) sum += cursor[i];
    __shared__ int lds[1024];
    lds[tid] = sum;
    __syncthreads();
    for (int off = 1; off < 1024; off <<= 1) {
        int t = (tid >= off) ? lds[tid - off] : 0;
        __syncthreads();
        lds[tid] += t;
        __syncthreads();
    }
    int run = lds[tid] - sum;
    for (int i = s; i < e; ++i) {
        int v = cursor[i];
        row_ptr[i] = run;
        cursor[i]  = run;
        run += v;
    }
    if (tid == T - 1) row_ptr[n] = run;
}

// pack (src, weight) into int2 so the gather loop does one 8B uniform load per edge
__global__ void scatter_kernel(const int* __restrict__ dst, const int* __restrict__ src,
                               const float* __restrict__ w, int* cursor,
                               int2* __restrict__ edges, int E) {
    int e = blockIdx.x * blockDim.x + threadIdx.x;
    if (e >= E) return;
    int d = dst[e];
    int p = atomicAdd(&cursor[d], 1);
    edges[p] = make_int2(src[e], __float_as_int(w[e]));
}

// ---------------- fused SPMM + GEMM ----------------
// grid = (N_NODES/NPB, BATCH): b varies slowest -> concurrent blocks gather from
// one 12.8 MB batch slice (L3-resident). Block: 8 waves, wave = node, lane = channel.

__global__ __launch_bounds__(NTHREADS) void cheb_first(
        const float* __restrict__ x,          // [B,N,C]
        const float* __restrict__ W,          // W0,W1 used
        const float* __restrict__ bias,
        const int* __restrict__ row_ptr,
        const int2* __restrict__ edges,
        float* __restrict__ t1,
        float* __restrict__ out) {
    __shared__ float sW0[WSZ];
    __shared__ float sW1[WSZ];
    __shared__ float st0[NTHREADS];
    __shared__ float st1[NTHREADS];

    const int tid = threadIdx.x;
    for (int i = tid; i < WSZ; i += NTHREADS) { sW0[i] = W[i]; sW1[i] = W[WSZ + i]; }

    const int wave = tid >> 6, c = tid & 63;
    const int n = blockIdx.x * NPB + wave;
    const int b = blockIdx.y;
    const int bn = b * (N_NODES * CH);
    const int il = n * CH + c;
    const float t0v = x[bn + il];

    float acc = 0.f;
    int p = row_ptr[n];
    const int end = row_ptr[n + 1];
    for (; p + 4 <= end; p += 4) {
        int2 e0 = edges[p], e1 = edges[p + 1], e2 = edges[p + 2], e3 = edges[p + 3];
        float g0 = x[bn + e0.x * CH + c];
        float g1 = x[bn + e1.x * CH + c];
        float g2 = x[bn + e2.x * CH + c];
        float g3 = x[bn + e3.x * CH + c];
        acc += __int_as_float(e0.y) * g0 + __int_as_float(e1.y) * g1
             + __int_as_float(e2.y) * g2 + __int_as_float(e3.y) * g3;
    }
    for (; p < end; ++p) {
        int2 e = edges[p];
        acc += __int_as_float(e.y) * x[bn + e.x * CH + c];
    }
    t1[bn + il] = acc;

    st0[tid] = t0v;
    st1[tid] = acc;
    __syncthreads();

    float o = bias[c];
    const int base = wave * CH;
#pragma unroll
    for (int cc = 0; cc < CH; ++cc) {
        o += st0[base + cc] * sW0[cc * CH + c] + st1[base + cc] * sW1[cc * CH + c];
    }
    out[bn + il] = o;
}

// T_next = 2*L*t_cur - t_prev ; out += T_next @ Wk. t_next may alias t_prev.
__global__ __launch_bounds__(NTHREADS) void cheb_step(
        const float* __restrict__ t_cur,
        const float* t_prev,                  // may alias t_next
        float* t_next,
        const float* __restrict__ Wk,
        const int* __restrict__ row_ptr,
        const int2* __restrict__ edges,
        float* __restrict__ out,
        int write_t) {
    __shared__ float sW[WSZ];
    __shared__ float st[NTHREADS];

    const int tid = threadIdx.x;
    for (int i = tid; i < WSZ; i += NTHREADS) sW[i] = Wk[i];

    const int wave = tid >> 6, c = tid & 63;
    const int n = blockIdx.x * NPB + wave;
    const int b = blockIdx.y;
    const int bn = b * (N_NODES * CH);
    const int il = n * CH + c;
    const float prevv = t_prev[bn + il];

    float acc = 0.f;
    int p = row_ptr[n];
    const int end = row_ptr[n + 1];
    for (; p + 4 <= end; p += 4) {
        int2 e0 = edges[p], e1 = edges[p + 1], e2 = edges[p + 2], e3 = edges[p + 3];
        float g0 = t_cur[bn + e0.x * CH + c];
        float g1 = t_cur[bn + e1.x * CH + c];
        float g2 = t_cur[bn + e2.x * CH + c];
        float g3 = t_cur[bn + e3.x * CH + c];
        acc += __int_as_float(e0.y) * g0 + __int_as_float(e1.y) * g1
             + __int_as_float(e2.y) * g2 + __int_as_float(e3.y) * g3;
    }
    for (; p < end; ++p) {
        int2 e = edges[p];
        acc += __int_as_float(e.y) * t_cur[bn + e.x * CH + c];
    }
    const float tn = 2.f * acc - prevv;
    if (write_t) t_next[bn + il] = tn;

    st[tid] = tn;
    __syncthreads();

    float o = 0.f;
    const int base = wave * CH;
#pragma unroll
    for (int cc = 0; cc < CH; ++cc) {
        o += st[base + cc] * sW[cc * CH + c];
    }
    out[bn + il] += o;
}

extern "C" void kernel_launch(void* const* d_in, const int* in_sizes, int n_in,
                              void* d_out, int out_size, void* d_ws, size_t ws_size,
                              hipStream_t stream) {
    const float* x    = (const float*)d_in[0];   // [B,N,C]
    const int*   ei   = (const int*)d_in[1];     // [2,E]: row0=dst, row1=src
    const float* ew   = (const float*)d_in[2];   // [E]
    const float* W    = (const float*)d_in[3];   // [K,64,64]
    const float* bias = (const float*)d_in[4];   // [64]
    float* out = (float*)d_out;

    const int* dst = ei;
    const int* src = ei + N_EDGES;

    // ---- workspace layout ----
    char* ws = (char*)d_ws;
    size_t off = 0;
    const size_t TBUF = (size_t)BATCH * N_NODES * CH * sizeof(float);  // 102.4 MB
    float* bufA = (float*)(ws + off); off += TBUF;
    float* bufB = (float*)(ws + off); off += TBUF;
    int*   row_ptr = (int*)(ws + off); off += ((N_NODES + 1) * sizeof(int) + 255) / 256 * 256;
    int*   cursor  = (int*)(ws + off); off += ((size_t)N_NODES * sizeof(int) + 255) / 256 * 256;
    int2*  edges   = (int2*)(ws + off); off += (size_t)N_EDGES * sizeof(int2);
    (void)ws_size; (void)off;

    // ---- CSR build ----
    hipMemsetAsync(cursor, 0, (size_t)N_NODES * sizeof(int), stream);
    hist_kernel<<<(N_EDGES + 255) / 256, 256, 0, stream>>>(dst, cursor, N_EDGES);
    scan_kernel<<<1, 1024, 0, stream>>>(cursor, row_ptr, N_NODES);
    scatter_kernel<<<(N_EDGES + 255) / 256, 256, 0, stream>>>(dst, src, ew, cursor,
                                                              edges, N_EDGES);

    const dim3 grid(N_NODES / NPB, BATCH);

    // k = 0,1 fused: t1 = Lx -> bufA ; out = bias + x@W0 + t1@W1
    cheb_first<<<grid, NTHREADS, 0, stream>>>(x, W, bias, row_ptr, edges, bufA, out);
    // k = 2: t2 = 2*L*t1 - x -> bufB
    cheb_step<<<grid, NTHREADS, 0, stream>>>(bufA, x, bufB, W + 2 * WSZ,
                                             row_ptr, edges, out, 1);
    // k = 3: t3 = 2*L*t2 - t1 -> bufA (in place)
    cheb_step<<<grid, NTHREADS, 0, stream>>>(bufB, bufA, bufA, W + 3 * WSZ,
                                             row_ptr, edges, out, 1);
    // k = 4: t4 = 2*L*t3 - t2 -> bufB (in place)
    cheb_step<<<grid, NTHREADS, 0, stream>>>(bufA, bufB, bufB, W + 4 * WSZ,
                                             row_ptr, edges, out, 1);
    // k = 5: t5 = 2*L*t4 - t3 ; no t-write
    cheb_step<<<grid, NTHREADS, 0, stream>>>(bufB, bufA, bufA, W + 5 * WSZ,
                                             row_ptr, edges, out, 0);
}

// Round 4
// 1346.450 us; speedup vs baseline: 1.8596x; 1.8596x over previous
//
#include <hip/hip_runtime.h>

#define N_NODES 50000
#define N_EDGES 800000
#define BATCH 8
#define CH 64
#define WSZ (CH * CH)
#define NROWS (BATCH * N_NODES)          // 400000 GEMM rows
#define TELEMS ((size_t)NROWS * CH)      // 25.6M elems per t-buffer
#define EDGE_CHUNK 128

typedef unsigned short u16;
typedef short bf16x8 __attribute__((ext_vector_type(8)));
typedef float f32x4 __attribute__((ext_vector_type(4)));
typedef unsigned short u16x4 __attribute__((ext_vector_type(4)));

__device__ __forceinline__ u16 f2bf(float f) {          // RNE
    unsigned x = __float_as_uint(f);
    return (u16)((x + 0x7fffu + ((x >> 16) & 1u)) >> 16);
}
__device__ __forceinline__ float b2f(u16 u) {
    return __uint_as_float(((unsigned)u) << 16);
}

// ---------------- CSR build ----------------

__global__ void hist_kernel(const int* __restrict__ dst, int* __restrict__ cursor, int E) {
    int e = blockIdx.x * blockDim.x + threadIdx.x;
    if (e < E) atomicAdd(&cursor[dst[e]], 1);
}

__global__ void scan_kernel(int* cursor, int* __restrict__ row_ptr, int n) {
    const int T = 1024;
    int tid = threadIdx.x;
    int per = (n + T - 1) / T;
    int s = tid * per;
    int e = s + per; if (e > n) e = n;
    int sum = 0;
    for (int i = s; i < e; ++i) sum += cursor[i];
    __shared__ int lds[1024];
    lds[tid] = sum;
    __syncthreads();
    for (int off = 1; off < 1024; off <<= 1) {
        int t = (tid >= off) ? lds[tid - off] : 0;
        __syncthreads();
        lds[tid] += t;
        __syncthreads();
    }
    int run = lds[tid] - sum;
    for (int i = s; i < e; ++i) {
        int v = cursor[i];
        row_ptr[i] = run;
        cursor[i]  = run;
        run += v;
    }
    if (tid == T - 1) row_ptr[n] = run;
}

__global__ void scatter_kernel(const int* __restrict__ dst, const int* __restrict__ src,
                               const float* __restrict__ w, int* cursor,
                               int2* __restrict__ edges, int E) {
    int e = blockIdx.x * blockDim.x + threadIdx.x;
    if (e >= E) return;
    int d = dst[e];
    int p = atomicAdd(&cursor[d], 1);
    edges[p] = make_int2(src[e], __float_as_int(w[e]));
}

// ---------------- fp32 -> bf16 cast of x ----------------
__global__ __launch_bounds__(256) void cast_x(const float* __restrict__ x, u16* __restrict__ xb) {
    size_t i = ((size_t)blockIdx.x * 256 + threadIdx.x) * 4;
    f32x4 v = __builtin_nontemporal_load((const f32x4*)(x + i));
    u16x4 o;
    o.x = f2bf(v.x); o.y = f2bf(v.y); o.z = f2bf(v.z); o.w = f2bf(v.w);
    *(u16x4*)(xb + i) = o;   // cached: it's the first gather source
}

// ---------------- pack W into MFMA B-fragment layout ----------------
// frag id = (k*2 + cct)*4 + ct ; lane holds B[k=quad*8+j][col=ct*16+(lane&15)]
__global__ __launch_bounds__(256) void pack_w(const float* __restrict__ W, u16* __restrict__ wpack) {
    int id = blockIdx.x * 256 + threadIdx.x;     // 48 frags * 64 lanes = 3072
    if (id >= 48 * 64) return;
    int lane = id & 63, frag = id >> 6;
    int ct = frag & 3, cct = (frag >> 2) & 1, k = frag >> 3;
    int m = lane & 15, quad = lane >> 4;
    int c = ct * 16 + m;
#pragma unroll
    for (int j = 0; j < 8; ++j) {
        int cc = cct * 32 + quad * 8 + j;
        wpack[(size_t)id * 8 + j] = f2bf(W[k * WSZ + cc * CH + c]);
    }
}

// ---------------- SPMM step ----------------
// block = node n, 8 waves = 8 batches, lane = channel.
// tn = (HAS_PREV ? 2*L*tcur - tprev : L*tcur); write bf16 (cached).
// FUSE: out += tn @ Wk (fallback path only).
template <bool HAS_PREV, bool FUSE>
__global__ __launch_bounds__(512) void spmm_kernel(
        const u16* __restrict__ tcur,
        const u16* tprev,                 // may alias tnext (in-place)
        u16* tnext,
        const int* __restrict__ row_ptr,
        const int2* __restrict__ edges,
        const float* __restrict__ Wk,     // FUSE only
        float* out) {                     // FUSE only
    __shared__ int   s_src[EDGE_CHUNK];
    __shared__ float s_w[EDGE_CHUNK];
    __shared__ float sW[FUSE ? WSZ : 1];
    __shared__ float st[FUSE ? 512 : 1];

    const int tid = threadIdx.x;
    if (FUSE) {
        for (int i = tid; i < WSZ; i += 512) sW[i] = Wk[i];
    }

    const int n = blockIdx.x;
    const int wave = tid >> 6, c = tid & 63;
    const int bn = wave * (N_NODES * CH);
    const int idx = bn + n * CH + c;

    float acc = 0.f;
    const int beg = row_ptr[n], end = row_ptr[n + 1];
    for (int chunk = beg; chunk < end; chunk += EDGE_CHUNK) {
        int m = end - chunk; if (m > EDGE_CHUNK) m = EDGE_CHUNK;
        __syncthreads();
        if (tid < m) {
            int2 e = edges[chunk + tid];
            s_src[tid] = e.x;
            s_w[tid]   = __int_as_float(e.y);
        }
        __syncthreads();
        for (int j = 0; j < m; ++j) {
            acc += s_w[j] * b2f(tcur[bn + s_src[j] * CH + c]);
        }
    }

    float tn;
    if (HAS_PREV) {
        float pv = b2f(__builtin_nontemporal_load(&tprev[idx]));
        tn = 2.f * acc - pv;
    } else {
        tn = acc;
    }
    tnext[idx] = f2bf(tn);    // cached: next step's gather source

    if (FUSE) {
        st[tid] = tn;
        __syncthreads();
        float o = __builtin_nontemporal_load(&out[idx]);
        const int base = wave * CH;
#pragma unroll
        for (int cc = 0; cc < CH; ++cc) o += st[base + cc] * sW[cc * CH + c];
        __builtin_nontemporal_store(o, &out[idx]);
    }
}

// ---------------- final GEMM: out = bias + sum_k t_k @ W_k (MFMA bf16) ----------------
// wave = one 16-row tile, all 64 output cols. 256 threads = 4 tiles/block.
__global__ __launch_bounds__(256) void out_gemm(
        const u16* __restrict__ tbase, size_t tstride,
        const u16* __restrict__ wpack,
        const float* __restrict__ bias,
        float* __restrict__ out, int nk) {
    const int wave = threadIdx.x >> 6, lane = threadIdx.x & 63;
    const int tile = blockIdx.x * 4 + wave;          // 25000 tiles
    const int row0 = tile * 16;
    const int m = lane & 15, quad = lane >> 4;

    f32x4 acc[4];
#pragma unroll
    for (int ct = 0; ct < 4; ++ct) acc[ct] = (f32x4){0.f, 0.f, 0.f, 0.f};

    for (int k = 0; k < nk; ++k) {
        const u16* t = tbase + (size_t)k * tstride;
#pragma unroll
        for (int cct = 0; cct < 2; ++cct) {
            bf16x8 A = *(const bf16x8*)(t + (size_t)(row0 + m) * CH + cct * 32 + quad * 8);
#pragma unroll
            for (int ct = 0; ct < 4; ++ct) {
                bf16x8 B = *(const bf16x8*)(wpack + (size_t)(((k * 2 + cct) * 4 + ct) * 64 + lane) * 8);
                acc[ct] = __builtin_amdgcn_mfma_f32_16x16x32_bf16(A, B, acc[ct], 0, 0, 0);
            }
        }
    }

#pragma unroll
    for (int ct = 0; ct < 4; ++ct) {
        const int c = ct * 16 + m;
        const float bv = bias[c];
#pragma unroll
        for (int r = 0; r < 4; ++r) {
            int row = row0 + quad * 4 + r;
            __builtin_nontemporal_store(acc[ct][r] + bv, &out[(size_t)row * CH + c]);
        }
    }
}

extern "C" void kernel_launch(void* const* d_in, const int* in_sizes, int n_in,
                              void* d_out, int out_size, void* d_ws, size_t ws_size,
                              hipStream_t stream) {
    const float* x    = (const float*)d_in[0];   // [B,N,C]
    const int*   ei   = (const int*)d_in[1];     // [2,E]: row0=dst, row1=src
    const float* ew   = (const float*)d_in[2];   // [E]
    const float* W    = (const float*)d_in[3];   // [K,64,64]
    const float* bias = (const float*)d_in[4];   // [64]
    float* out = (float*)d_out;

    const int* dst = ei;
    const int* src = ei + N_EDGES;

    const size_t SB = TELEMS * sizeof(u16);      // 51.2 MB per t-buffer
    const size_t EXTRA = 2 * 200192 + (size_t)N_EDGES * sizeof(int2) + 49664;
    const size_t NEED_PRIMARY = 6 * SB + EXTRA;  // ~314.3 MB
    const bool primary = (ws_size >= NEED_PRIMARY);
    const int nbuf = primary ? 6 : 3;

    char* ws = (char*)d_ws;
    size_t off = 0;
    u16* tbase = (u16*)(ws + off); off += (size_t)nbuf * SB;   // t0(=x bf16), t1..
    int* row_ptr = (int*)(ws + off); off += 200192;
    int* cursor  = (int*)(ws + off); off += 200192;
    int2* edges  = (int2*)(ws + off); off += (size_t)N_EDGES * sizeof(int2);
    u16* wpack   = (u16*)(ws + off); off += 49664;
    (void)off; (void)n_in; (void)in_sizes; (void)out_size;

    // ---- CSR build + precompute ----
    (void)hipMemsetAsync(cursor, 0, (size_t)N_NODES * sizeof(int), stream);
    hist_kernel<<<(N_EDGES + 255) / 256, 256, 0, stream>>>(dst, cursor, N_EDGES);
    scan_kernel<<<1, 1024, 0, stream>>>(cursor, row_ptr, N_NODES);
    scatter_kernel<<<(N_EDGES + 255) / 256, 256, 0, stream>>>(dst, src, ew, cursor,
                                                              edges, N_EDGES);
    cast_x<<<(int)(TELEMS / 4 / 256), 256, 0, stream>>>(x, tbase);
    pack_w<<<12, 256, 0, stream>>>(W, wpack);

    u16* t0 = tbase;
    if (primary) {
        u16* t1 = tbase + 1 * TELEMS;
        u16* t2 = tbase + 2 * TELEMS;
        u16* t3 = tbase + 3 * TELEMS;
        u16* t4 = tbase + 4 * TELEMS;
        u16* t5 = tbase + 5 * TELEMS;
        spmm_kernel<false, false><<<N_NODES, 512, 0, stream>>>(t0, nullptr, t1, row_ptr, edges, nullptr, nullptr);
        spmm_kernel<true,  false><<<N_NODES, 512, 0, stream>>>(t1, t0, t2, row_ptr, edges, nullptr, nullptr);
        spmm_kernel<true,  false><<<N_NODES, 512, 0, stream>>>(t2, t1, t3, row_ptr, edges, nullptr, nullptr);
        spmm_kernel<true,  false><<<N_NODES, 512, 0, stream>>>(t3, t2, t4, row_ptr, edges, nullptr, nullptr);
        spmm_kernel<true,  false><<<N_NODES, 512, 0, stream>>>(t4, t3, t5, row_ptr, edges, nullptr, nullptr);
        out_gemm<<<NROWS / 16 / 4, 256, 0, stream>>>(tbase, TELEMS, wpack, bias, out, 6);
    } else {
        // fallback: 3 rotating buffers + fused out accumulation
        u16* bufA = tbase + 1 * TELEMS;
        u16* bufB = tbase + 2 * TELEMS;
        spmm_kernel<false, false><<<N_NODES, 512, 0, stream>>>(t0, nullptr, bufA, row_ptr, edges, nullptr, nullptr);
        out_gemm<<<NROWS / 16 / 4, 256, 0, stream>>>(tbase, TELEMS, wpack, bias, out, 2); // bias + t0@W0 + t1@W1
        spmm_kernel<true, true><<<N_NODES, 512, 0, stream>>>(bufA, t0,   bufB, row_ptr, edges, W + 2 * WSZ, out);
        spmm_kernel<true, true><<<N_NODES, 512, 0, stream>>>(bufB, bufA, bufA, row_ptr, edges, W + 3 * WSZ, out);
        spmm_kernel<true, true><<<N_NODES, 512, 0, stream>>>(bufA, bufB, bufB, row_ptr, edges, W + 4 * WSZ, out);
        spmm_kernel<true, true><<<N_NODES, 512, 0, stream>>>(bufB, bufA, bufA, row_ptr, edges, W + 5 * WSZ, out);
    }
}